// Round 2
// baseline (483.609 us; speedup 1.0000x reference)
//
#include <hip/hip_runtime.h>
#include <math.h>

typedef _Float16 h16;
typedef _Float16 h16x4 __attribute__((ext_vector_type(4)));
typedef _Float16 h16x8 __attribute__((ext_vector_type(8)));
typedef float    f32x4 __attribute__((ext_vector_type(4)));

#define Bsz 2
#define Tsz 2048
#define Dsz 1024
#define Hn  16
#define DH  64
#define NC  8          // scan chunks
#define CL  (Tsz/NC)   // 256 steps per chunk

// ---------------------------------------------------------------------------
// Convert the 7 weight matrices (each 1024x1024 f32) to f16, packed at dst.
// grid = 7*512 blocks, 256 thr, 8 elems/thr.
__global__ void cvt_w7(const float* __restrict__ s0, const float* __restrict__ s1,
                       const float* __restrict__ s2, const float* __restrict__ s3,
                       const float* __restrict__ s4, const float* __restrict__ s5,
                       const float* __restrict__ s6, h16* __restrict__ dst) {
    int seg = blockIdx.x >> 9;
    int li  = ((blockIdx.x & 511) << 8) + threadIdx.x;
    const float* sp;
    switch (seg) {
        case 0: sp = s0; break; case 1: sp = s1; break; case 2: sp = s2; break;
        case 3: sp = s3; break; case 4: sp = s4; break; case 5: sp = s5; break;
        default: sp = s6; break;
    }
    size_t e = (size_t)li * 8;
    f32x4 a = *(const f32x4*)(sp + e);
    f32x4 b = *(const f32x4*)(sp + e + 4);
    h16x8 o;
    #pragma unroll
    for (int j = 0; j < 4; ++j) { o[j] = (h16)a[j]; o[j + 4] = (h16)b[j]; }
    *(h16x8*)(dst + (size_t)seg * 1048576 + e) = o;
}

// ---------------------------------------------------------------------------
// Build x_shift in f16 (prepend zero row per batch). 8 elems/thr, grid 2048.
__global__ void mk_xs(const float* __restrict__ x, h16* __restrict__ xs) {
    int li = (blockIdx.x << 8) + threadIdx.x;
    size_t e = (size_t)li * 8;
    int tok = (int)(e >> 10);
    int t   = tok & (Tsz - 1);
    h16x8 o;
    if (t > 0) {
        f32x4 a = *(const f32x4*)(x + e - Dsz);
        f32x4 b = *(const f32x4*)(x + e - Dsz + 4);
        #pragma unroll
        for (int j = 0; j < 4; ++j) { o[j] = (h16)a[j]; o[j + 4] = (h16)b[j]; }
    } else {
        #pragma unroll
        for (int j = 0; j < 8; ++j) o[j] = (h16)0.f;
    }
    *(h16x8*)(xs + e) = o;
}

// ---------------------------------------------------------------------------
// 5-way lerp: a_X = xs + (x-xs)*(mix_X + dd*(1-mix_X)), f16 out. 4 elems/thr.
__global__ void lerp5(const float* __restrict__ x, const float* __restrict__ dd,
                      const float* __restrict__ mr, const float* __restrict__ mk,
                      const float* __restrict__ mv, const float* __restrict__ mg,
                      const float* __restrict__ mw,
                      h16* __restrict__ ar, h16* __restrict__ ak, h16* __restrict__ av,
                      h16* __restrict__ ag, h16* __restrict__ aw) {
    size_t e = ((size_t)blockIdx.x * 256 + threadIdx.x) * 4;
    int tok = (int)(e >> 10);
    int t   = tok & (Tsz - 1);
    int d   = (int)(e & (Dsz - 1));
    f32x4 xv = *(const f32x4*)(x + e);
    f32x4 xs;
    if (t > 0) xs = *(const f32x4*)(x + e - Dsz);
    else { xs[0] = xs[1] = xs[2] = xs[3] = 0.f; }
    f32x4 dv  = *(const f32x4*)(dd + e);
    f32x4 dxx = xv - xs;
    #define DOMIX(mp, outp) { \
        f32x4 mm = *(const f32x4*)(mp + d); \
        h16x4 ov; \
        _Pragma("unroll") \
        for (int jj = 0; jj < 4; ++jj) { \
            float m = mm[jj] + dv[jj] * (1.f - mm[jj]); \
            ov[jj] = (h16)(xs[jj] + dxx[jj] * m); \
        } \
        *(h16x4*)(outp + e) = ov; }
    DOMIX(mr, ar) DOMIX(mk, ak) DOMIX(mv, av) DOMIX(mg, ag) DOMIX(mw, aw)
    #undef DOMIX
}

// ---------------------------------------------------------------------------
// f16 MFMA GEMM: C[M=4096][N=1024] = A[M][K=1024] * W[N][K]^T, f32 out.
// 128x128 tile, BK=32, 4 waves of 64x64, 16x16x32 mfma.
// epi: 0=raw, 1=sigmoid(tanh(y)), 2=silu(y), 3=e^-0.5*sigmoid(y)
#define KP 40   // padded LDS row (elements) to break bank conflicts
__global__ __launch_bounds__(256) void gemm_bt(const h16* __restrict__ A,
                                               const h16* __restrict__ W,
                                               float* __restrict__ C, int epi) {
    __shared__ h16 As[128][KP];
    __shared__ h16 Bs[128][KP];
    const int tid  = threadIdx.x;
    const int lane = tid & 63;
    const int wave = tid >> 6;
    const int wm = (wave >> 1) * 64;
    const int wn = (wave & 1) * 64;
    const int bm = blockIdx.y * 128;
    const int bn = blockIdx.x * 128;
    const int K = 1024, N = 1024;

    f32x4 acc[4][4];
    #pragma unroll
    for (int a = 0; a < 4; ++a)
        #pragma unroll
        for (int b = 0; b < 4; ++b) acc[a][b] = (f32x4)(0.f);

    const int srow = tid >> 2;          // 0..63
    const int skc  = (tid & 3) * 8;     // 0,8,16,24

    for (int k0 = 0; k0 < K; k0 += 32) {
        f32x4 a0 = *(const f32x4*)(A + (size_t)(bm + srow)      * K + k0 + skc);
        f32x4 a1 = *(const f32x4*)(A + (size_t)(bm + srow + 64) * K + k0 + skc);
        f32x4 b0 = *(const f32x4*)(W + (size_t)(bn + srow)      * K + k0 + skc);
        f32x4 b1 = *(const f32x4*)(W + (size_t)(bn + srow + 64) * K + k0 + skc);
        __syncthreads();
        *(f32x4*)(&As[srow][skc])      = a0;
        *(f32x4*)(&As[srow + 64][skc]) = a1;
        *(f32x4*)(&Bs[srow][skc])      = b0;
        *(f32x4*)(&Bs[srow + 64][skc]) = b1;
        __syncthreads();
        h16x8 af[4], bfr[4];
        #pragma unroll
        for (int mi = 0; mi < 4; ++mi)
            af[mi] = *(const h16x8*)(&As[wm + mi * 16 + (lane & 15)][(lane >> 4) * 8]);
        #pragma unroll
        for (int ni = 0; ni < 4; ++ni)
            bfr[ni] = *(const h16x8*)(&Bs[wn + ni * 16 + (lane & 15)][(lane >> 4) * 8]);
        #pragma unroll
        for (int mi = 0; mi < 4; ++mi)
            #pragma unroll
            for (int ni = 0; ni < 4; ++ni)
                acc[mi][ni] = __builtin_amdgcn_mfma_f32_16x16x32_f16(
                    af[mi], bfr[ni], acc[mi][ni], 0, 0, 0);
    }

    const int colb = bn + wn + (lane & 15);
    const int rowb = bm + wm + (lane >> 4) * 4;
    #pragma unroll
    for (int mi = 0; mi < 4; ++mi)
        #pragma unroll
        for (int ni = 0; ni < 4; ++ni)
            #pragma unroll
            for (int j = 0; j < 4; ++j) {
                float y = acc[mi][ni][j];
                if (epi == 1)      { float th = tanhf(y); y = 1.f / (1.f + __expf(-th)); }
                else if (epi == 2) { y = y / (1.f + __expf(-y)); }
                else if (epi == 3) { y = 0.60653065971263342f / (1.f + __expf(-y)); }
                C[(size_t)(rowb + mi * 16 + j) * N + colb + ni * 16] = y;
            }
}

// ---------------------------------------------------------------------------
// WKV scan, chunked. state[i][j] = state[i][j]*ew[i] + k[i]*v[j]; o[i]=sum_j st*r[j]
// Block: 256 thr; thread t: row i=t>>2 (0..63), q=t&3 covers j in [q*16, q*16+16).
__global__ __launch_bounds__(256) void wkv_pass1(const float* __restrict__ kk,
                                                 const float* __restrict__ vv,
                                                 const float* __restrict__ ew,
                                                 float* __restrict__ Abuf,
                                                 float* __restrict__ Pbuf) {
    int blk = blockIdx.x;            // bh*NC + c
    int bh = blk >> 3, c = blk & 7;
    int b = bh >> 4, h = bh & 15;
    int tid = threadIdx.x;
    int i = tid >> 2, q = tid & 3, j0 = q * 16;
    float st[16];
    #pragma unroll
    for (int jj = 0; jj < 16; ++jj) st[jj] = 0.f;
    float pp = 1.f;
    size_t base = ((size_t)b * Tsz + (size_t)c * CL) * Dsz + h * DH;
    for (int tt = 0; tt < CL; ++tt) {
        float ewi = ew[base + i];
        float ki  = kk[base + i];
        const f32x4* vp = (const f32x4*)(vv + base + j0);
        f32x4 v0 = vp[0], v1 = vp[1], v2 = vp[2], v3 = vp[3];
        #pragma unroll
        for (int jj = 0; jj < 4; ++jj) {
            st[jj]      = fmaf(st[jj],      ewi, ki * v0[jj]);
            st[jj + 4]  = fmaf(st[jj + 4],  ewi, ki * v1[jj]);
            st[jj + 8]  = fmaf(st[jj + 8],  ewi, ki * v2[jj]);
            st[jj + 12] = fmaf(st[jj + 12], ewi, ki * v3[jj]);
        }
        pp *= ewi;
        base += Dsz;
    }
    size_t ob = (size_t)blk * 4096 + (size_t)i * 64 + j0;
    f32x4* op = (f32x4*)(Abuf + ob);
    #pragma unroll
    for (int g = 0; g < 4; ++g) {
        f32x4 s;
        #pragma unroll
        for (int jj = 0; jj < 4; ++jj) s[jj] = st[g * 4 + jj];
        op[g] = s;
    }
    if (q == 0) Pbuf[blk * 64 + i] = pp;
}

__global__ __launch_bounds__(256) void wkv_combine(const float* __restrict__ Abuf,
                                                   const float* __restrict__ Pbuf,
                                                   float* __restrict__ Sbuf) {
    int bh = blockIdx.x;
    int tid = threadIdx.x;
    int i = tid >> 2, q = tid & 3, j0 = q * 16;
    float s[16];
    #pragma unroll
    for (int jj = 0; jj < 16; ++jj) s[jj] = 0.f;
    for (int c = 0; c < NC; ++c) {
        size_t ob = ((size_t)(bh * NC + c)) * 4096 + (size_t)i * 64 + j0;
        f32x4* sp = (f32x4*)(Sbuf + ob);
        #pragma unroll
        for (int g = 0; g < 4; ++g) {
            f32x4 t;
            #pragma unroll
            for (int jj = 0; jj < 4; ++jj) t[jj] = s[g * 4 + jj];
            sp[g] = t;
        }
        if (c < NC - 1) {
            float pp = Pbuf[(bh * NC + c) * 64 + i];
            const f32x4* ap = (const f32x4*)(Abuf + ob);
            f32x4 a0 = ap[0], a1 = ap[1], a2 = ap[2], a3 = ap[3];
            #pragma unroll
            for (int jj = 0; jj < 4; ++jj) {
                s[jj]      = s[jj]      * pp + a0[jj];
                s[jj + 4]  = s[jj + 4]  * pp + a1[jj];
                s[jj + 8]  = s[jj + 8]  * pp + a2[jj];
                s[jj + 12] = s[jj + 12] * pp + a3[jj];
            }
        }
    }
}

__global__ __launch_bounds__(256) void wkv_pass2(const float* __restrict__ rr,
                                                 const float* __restrict__ kk,
                                                 const float* __restrict__ vv,
                                                 const float* __restrict__ ew,
                                                 const float* __restrict__ Sbuf,
                                                 float* __restrict__ o) {
    int blk = blockIdx.x;
    int bh = blk >> 3, c = blk & 7;
    int b = bh >> 4, h = bh & 15;
    int tid = threadIdx.x;
    int i = tid >> 2, q = tid & 3, j0 = q * 16;
    float st[16];
    {
        size_t ob = (size_t)blk * 4096 + (size_t)i * 64 + j0;
        const f32x4* sp = (const f32x4*)(Sbuf + ob);
        f32x4 s0 = sp[0], s1 = sp[1], s2 = sp[2], s3 = sp[3];
        #pragma unroll
        for (int jj = 0; jj < 4; ++jj) {
            st[jj] = s0[jj]; st[jj + 4] = s1[jj]; st[jj + 8] = s2[jj]; st[jj + 12] = s3[jj];
        }
    }
    size_t base = ((size_t)b * Tsz + (size_t)c * CL) * Dsz + h * DH;
    for (int tt = 0; tt < CL; ++tt) {
        float ewi = ew[base + i];
        float ki  = kk[base + i];
        const f32x4* vp = (const f32x4*)(vv + base + j0);
        const f32x4* rp = (const f32x4*)(rr + base + j0);
        f32x4 v0 = vp[0], v1 = vp[1], v2 = vp[2], v3 = vp[3];
        f32x4 r0 = rp[0], r1 = rp[1], r2 = rp[2], r3 = rp[3];
        float po = 0.f;
        #pragma unroll
        for (int jj = 0; jj < 4; ++jj) {
            st[jj]      = fmaf(st[jj],      ewi, ki * v0[jj]);
            st[jj + 4]  = fmaf(st[jj + 4],  ewi, ki * v1[jj]);
            st[jj + 8]  = fmaf(st[jj + 8],  ewi, ki * v2[jj]);
            st[jj + 12] = fmaf(st[jj + 12], ewi, ki * v3[jj]);
            po = fmaf(st[jj],      r0[jj], po);
            po = fmaf(st[jj + 4],  r1[jj], po);
            po = fmaf(st[jj + 8],  r2[jj], po);
            po = fmaf(st[jj + 12], r3[jj], po);
        }
        po += __shfl_xor(po, 1, 64);
        po += __shfl_xor(po, 2, 64);
        if (q == 0) o[base + i] = po;
        base += Dsz;
    }
}

// ---------------------------------------------------------------------------
// GroupNorm(16 groups of 64) + gate by silu(g) + f16 convert. 1 wave = 1 group.
__global__ __launch_bounds__(256) void gn_gate(const float* __restrict__ o,
                                               const float* __restrict__ g,
                                               const float* __restrict__ gnw,
                                               const float* __restrict__ gnb,
                                               h16* __restrict__ out) {
    int wave = threadIdx.x >> 6, lane = threadIdx.x & 63;
    int grp = blockIdx.x * 4 + wave;     // tok*16 + h
    int h = grp & 15;
    float val = o[(size_t)grp * 64 + lane];
    float s = val, s2 = val * val;
    #pragma unroll
    for (int m = 1; m < 64; m <<= 1) {
        s  += __shfl_xor(s, m, 64);
        s2 += __shfl_xor(s2, m, 64);
    }
    float mean = s * (1.f / 64.f);
    float var  = s2 * (1.f / 64.f) - mean * mean;
    float y = (val - mean) * rsqrtf(var + 0.00064f);
    int d = h * 64 + lane;
    y = y * gnw[d] + gnb[d];
    y *= g[(size_t)grp * 64 + lane];
    out[(size_t)grp * 64 + lane] = (h16)y;
}

// ---------------------------------------------------------------------------
extern "C" void kernel_launch(void* const* d_in, const int* in_sizes, int n_in,
                              void* d_out, int out_size, void* d_ws, size_t ws_size,
                              hipStream_t stream) {
    const float* x      = (const float*)d_in[0];
    const float* ddw    = (const float*)d_in[1];
    const float* mix_r  = (const float*)d_in[2];
    const float* mix_k  = (const float*)d_in[3];
    const float* mix_v  = (const float*)d_in[4];
    const float* mix_g  = (const float*)d_in[5];
    const float* mix_w  = (const float*)d_in[6];
    const float* r_w    = (const float*)d_in[7];
    const float* k_w    = (const float*)d_in[8];
    const float* v_w    = (const float*)d_in[9];
    const float* g_w    = (const float*)d_in[10];
    const float* w_w    = (const float*)d_in[11];
    const float* out_w  = (const float*)d_in[12];
    const float* gnw    = (const float*)d_in[13];
    const float* gnb    = (const float*)d_in[14];

    size_t off = 0;
    char* wsb = (char*)d_ws;
    auto alloc = [&](size_t bytes) {
        void* p = wsb + off;
        off += (bytes + 255) & ~(size_t)255;
        return p;
    };
    const size_t NT = (size_t)Bsz * Tsz;          // 4096 tokens
    h16*   wb    = (h16*)  alloc(7 * 1048576 * sizeof(h16));
    h16*   xs    = (h16*)  alloc(NT * Dsz * sizeof(h16));
    float* dd    = (float*)alloc(NT * Dsz * sizeof(float));
    h16*   a_r   = (h16*)  alloc(NT * Dsz * sizeof(h16));
    h16*   a_k   = (h16*)  alloc(NT * Dsz * sizeof(h16));
    h16*   a_v   = (h16*)  alloc(NT * Dsz * sizeof(h16));
    h16*   a_g   = (h16*)  alloc(NT * Dsz * sizeof(h16));
    h16*   a_w   = (h16*)  alloc(NT * Dsz * sizeof(h16));
    float* rb    = (float*)alloc(NT * Dsz * sizeof(float));
    float* kb    = (float*)alloc(NT * Dsz * sizeof(float));
    float* vb    = (float*)alloc(NT * Dsz * sizeof(float));
    float* gb    = (float*)alloc(NT * Dsz * sizeof(float));
    float* ewb   = (float*)alloc(NT * Dsz * sizeof(float));
    float* Abuf  = (float*)alloc((size_t)32 * NC * 4096 * sizeof(float));
    float* Pbuf  = (float*)alloc((size_t)32 * NC * 64 * sizeof(float));
    float* Sbuf  = (float*)alloc((size_t)32 * NC * 4096 * sizeof(float));
    float* obuf  = (float*)alloc(NT * Dsz * sizeof(float));
    h16*   gated = (h16*)  alloc(NT * Dsz * sizeof(h16));

    // 1. weights -> f16
    cvt_w7<<<7 * 512, 256, 0, stream>>>(ddw, r_w, k_w, v_w, g_w, w_w, out_w, wb);
    // 2. x_shift -> f16
    mk_xs<<<2048, 256, 0, stream>>>(x, xs);
    // 3. dd = sigmoid(tanh(xs @ ddw^T))
    dim3 gg(8, 32);
    gemm_bt<<<gg, 256, 0, stream>>>(xs, wb, dd, 1);
    // 4. 5-way lerp -> f16 activations
    lerp5<<<4096, 256, 0, stream>>>(x, dd, mix_r, mix_k, mix_v, mix_g, mix_w,
                                    a_r, a_k, a_v, a_g, a_w);
    // 5. projections
    gemm_bt<<<gg, 256, 0, stream>>>(a_r, wb + 1 * 1048576, rb, 0);
    gemm_bt<<<gg, 256, 0, stream>>>(a_k, wb + 2 * 1048576, kb, 0);
    gemm_bt<<<gg, 256, 0, stream>>>(a_v, wb + 3 * 1048576, vb, 0);
    gemm_bt<<<gg, 256, 0, stream>>>(a_g, wb + 4 * 1048576, gb, 2);   // silu
    gemm_bt<<<gg, 256, 0, stream>>>(a_w, wb + 5 * 1048576, ewb, 3);  // exp(w) = e^-.5*sigmoid
    // 6-8. chunked WKV scan
    wkv_pass1<<<32 * NC, 256, 0, stream>>>(kb, vb, ewb, Abuf, Pbuf);
    wkv_combine<<<32, 256, 0, stream>>>(Abuf, Pbuf, Sbuf);
    wkv_pass2<<<32 * NC, 256, 0, stream>>>(rb, kb, vb, ewb, Sbuf, obuf);
    // 9. GroupNorm + gate
    gn_gate<<<(int)(NT * Hn / 4), 256, 0, stream>>>(obuf, gb, gnw, gnb, gated);
    // 10. output projection
    gemm_bt<<<gg, 256, 0, stream>>>(gated, wb + 6 * 1048576, (float*)d_out, 0);
    (void)in_sizes; (void)n_in; (void)out_size; (void)ws_size;
}

// Round 3
// 428.611 us; speedup vs baseline: 1.1283x; 1.1283x over previous
//
#include <hip/hip_runtime.h>
#include <math.h>

typedef _Float16 h16;
typedef _Float16 h16x4 __attribute__((ext_vector_type(4)));
typedef _Float16 h16x8 __attribute__((ext_vector_type(8)));
typedef float    f32x4 __attribute__((ext_vector_type(4)));

#define Bsz 2
#define Tsz 2048
#define Dsz 1024
#define Hn  16
#define DH  64
#define NC  32         // scan chunks
#define NCSH 5
#define CL  (Tsz/NC)   // 64 steps per chunk

// ---------------------------------------------------------------------------
// Convert the 7 weight matrices (each 1024x1024 f32) to f16, packed at dst.
__global__ void cvt_w7(const float* __restrict__ s0, const float* __restrict__ s1,
                       const float* __restrict__ s2, const float* __restrict__ s3,
                       const float* __restrict__ s4, const float* __restrict__ s5,
                       const float* __restrict__ s6, h16* __restrict__ dst) {
    int seg = blockIdx.x >> 9;
    int li  = ((blockIdx.x & 511) << 8) + threadIdx.x;
    const float* sp;
    switch (seg) {
        case 0: sp = s0; break; case 1: sp = s1; break; case 2: sp = s2; break;
        case 3: sp = s3; break; case 4: sp = s4; break; case 5: sp = s5; break;
        default: sp = s6; break;
    }
    size_t e = (size_t)li * 8;
    f32x4 a = *(const f32x4*)(sp + e);
    f32x4 b = *(const f32x4*)(sp + e + 4);
    h16x8 o;
    #pragma unroll
    for (int j = 0; j < 4; ++j) { o[j] = (h16)a[j]; o[j + 4] = (h16)b[j]; }
    *(h16x8*)(dst + (size_t)seg * 1048576 + e) = o;
}

// ---------------------------------------------------------------------------
__global__ void mk_xs(const float* __restrict__ x, h16* __restrict__ xs) {
    int li = (blockIdx.x << 8) + threadIdx.x;
    size_t e = (size_t)li * 8;
    int tok = (int)(e >> 10);
    int t   = tok & (Tsz - 1);
    h16x8 o;
    if (t > 0) {
        f32x4 a = *(const f32x4*)(x + e - Dsz);
        f32x4 b = *(const f32x4*)(x + e - Dsz + 4);
        #pragma unroll
        for (int j = 0; j < 4; ++j) { o[j] = (h16)a[j]; o[j + 4] = (h16)b[j]; }
    } else {
        #pragma unroll
        for (int j = 0; j < 8; ++j) o[j] = (h16)0.f;
    }
    *(h16x8*)(xs + e) = o;
}

// ---------------------------------------------------------------------------
__global__ void lerp5(const float* __restrict__ x, const float* __restrict__ dd,
                      const float* __restrict__ mr, const float* __restrict__ mk,
                      const float* __restrict__ mv, const float* __restrict__ mg,
                      const float* __restrict__ mw,
                      h16* __restrict__ ar, h16* __restrict__ ak, h16* __restrict__ av,
                      h16* __restrict__ ag, h16* __restrict__ aw) {
    size_t e = ((size_t)blockIdx.x * 256 + threadIdx.x) * 4;
    int tok = (int)(e >> 10);
    int t   = tok & (Tsz - 1);
    int d   = (int)(e & (Dsz - 1));
    f32x4 xv = *(const f32x4*)(x + e);
    f32x4 xs;
    if (t > 0) xs = *(const f32x4*)(x + e - Dsz);
    else { xs[0] = xs[1] = xs[2] = xs[3] = 0.f; }
    f32x4 dv  = *(const f32x4*)(dd + e);
    f32x4 dxx = xv - xs;
    #define DOMIX(mp, outp) { \
        f32x4 mm = *(const f32x4*)(mp + d); \
        h16x4 ov; \
        _Pragma("unroll") \
        for (int jj = 0; jj < 4; ++jj) { \
            float m = mm[jj] + dv[jj] * (1.f - mm[jj]); \
            ov[jj] = (h16)(xs[jj] + dxx[jj] * m); \
        } \
        *(h16x4*)(outp + e) = ov; }
    DOMIX(mr, ar) DOMIX(mk, ak) DOMIX(mv, av) DOMIX(mg, ag) DOMIX(mw, aw)
    #undef DOMIX
}

// ---------------------------------------------------------------------------
// f16 MFMA GEMM body: C[4096][1024] = A[4096][1024] * W[1024][1024]^T, f32 out.
// 128x128 tile, BK=32, 4 waves of 64x64, 16x16x32 mfma.
// epi: 0=raw, 1=sigmoid(tanh(y)), 2=silu(y), 3=e^-0.5*sigmoid(y)
#define KP 40
__device__ __forceinline__ void gemm_body(const h16* __restrict__ A,
                                          const h16* __restrict__ W,
                                          float* __restrict__ C, int epi) {
    __shared__ h16 As[128][KP];
    __shared__ h16 Bs[128][KP];
    const int tid  = threadIdx.x;
    const int lane = tid & 63;
    const int wave = tid >> 6;
    const int wm = (wave >> 1) * 64;
    const int wn = (wave & 1) * 64;
    const int bm = blockIdx.y * 128;
    const int bn = blockIdx.x * 128;
    const int K = 1024, N = 1024;

    f32x4 acc[4][4];
    #pragma unroll
    for (int a = 0; a < 4; ++a)
        #pragma unroll
        for (int b = 0; b < 4; ++b) acc[a][b] = (f32x4)(0.f);

    const int srow = tid >> 2;
    const int skc  = (tid & 3) * 8;

    for (int k0 = 0; k0 < K; k0 += 32) {
        f32x4 a0 = *(const f32x4*)(A + (size_t)(bm + srow)      * K + k0 + skc);
        f32x4 a1 = *(const f32x4*)(A + (size_t)(bm + srow + 64) * K + k0 + skc);
        f32x4 b0 = *(const f32x4*)(W + (size_t)(bn + srow)      * K + k0 + skc);
        f32x4 b1 = *(const f32x4*)(W + (size_t)(bn + srow + 64) * K + k0 + skc);
        __syncthreads();
        *(f32x4*)(&As[srow][skc])      = a0;
        *(f32x4*)(&As[srow + 64][skc]) = a1;
        *(f32x4*)(&Bs[srow][skc])      = b0;
        *(f32x4*)(&Bs[srow + 64][skc]) = b1;
        __syncthreads();
        h16x8 af[4], bfr[4];
        #pragma unroll
        for (int mi = 0; mi < 4; ++mi)
            af[mi] = *(const h16x8*)(&As[wm + mi * 16 + (lane & 15)][(lane >> 4) * 8]);
        #pragma unroll
        for (int ni = 0; ni < 4; ++ni)
            bfr[ni] = *(const h16x8*)(&Bs[wn + ni * 16 + (lane & 15)][(lane >> 4) * 8]);
        #pragma unroll
        for (int mi = 0; mi < 4; ++mi)
            #pragma unroll
            for (int ni = 0; ni < 4; ++ni)
                acc[mi][ni] = __builtin_amdgcn_mfma_f32_16x16x32_f16(
                    af[mi], bfr[ni], acc[mi][ni], 0, 0, 0);
    }

    const int colb = bn + wn + (lane & 15);
    const int rowb = bm + wm + (lane >> 4) * 4;
    #pragma unroll
    for (int mi = 0; mi < 4; ++mi)
        #pragma unroll
        for (int ni = 0; ni < 4; ++ni)
            #pragma unroll
            for (int j = 0; j < 4; ++j) {
                float y = acc[mi][ni][j];
                if (epi == 1)      { float th = tanhf(y); y = 1.f / (1.f + __expf(-th)); }
                else if (epi == 2) { y = y / (1.f + __expf(-y)); }
                else if (epi == 3) { y = 0.60653065971263342f / (1.f + __expf(-y)); }
                C[(size_t)(rowb + mi * 16 + j) * N + colb + ni * 16] = y;
            }
}

__global__ __launch_bounds__(256) void gemm_bt(const h16* __restrict__ A,
                                               const h16* __restrict__ W,
                                               float* __restrict__ C, int epi) {
    gemm_body(A, W, C, epi);
}

// Batched: z selects {A, C, epi}; W = Wb + (z+1)*1M.  epi map {0,0,0,2,3}.
__global__ __launch_bounds__(256) void gemm5(const h16* __restrict__ A0, const h16* __restrict__ A1,
                                             const h16* __restrict__ A2, const h16* __restrict__ A3,
                                             const h16* __restrict__ A4, const h16* __restrict__ Wb,
                                             float* __restrict__ C0, float* __restrict__ C1,
                                             float* __restrict__ C2, float* __restrict__ C3,
                                             float* __restrict__ C4) {
    int z = blockIdx.z;
    const h16* A; float* C; int epi;
    switch (z) {
        case 0: A = A0; C = C0; epi = 0; break;
        case 1: A = A1; C = C1; epi = 0; break;
        case 2: A = A2; C = C2; epi = 0; break;
        case 3: A = A3; C = C3; epi = 2; break;
        default: A = A4; C = C4; epi = 3; break;
    }
    gemm_body(A, Wb + (size_t)(z + 1) * 1048576, C, epi);
}

// ---------------------------------------------------------------------------
// WKV scan, chunked, software-pipelined 1 load ahead.
// Thread t: row i=t>>2 (0..63), q=t&3 covers j in [q*16, q*16+16).
// NOTE: each pass intentionally loads one row past its chunk (prefetch of a
// value never used on the last iteration) — the ws layout guarantees that
// address is mapped (rb<kb<vb<gb<ewb<obuf are contiguous).
__global__ __launch_bounds__(256) void wkv_pass1(const float* __restrict__ kk,
                                                 const float* __restrict__ vv,
                                                 const float* __restrict__ ew,
                                                 float* __restrict__ Abuf,
                                                 float* __restrict__ Pbuf) {
    int blk = blockIdx.x;            // bh*NC + c
    int bh = blk >> NCSH, c = blk & (NC - 1);
    int b = bh >> 4, h = bh & 15;
    int tid = threadIdx.x;
    int i = tid >> 2, q = tid & 3, j0 = q * 16;
    float st[16];
    #pragma unroll
    for (int jj = 0; jj < 16; ++jj) st[jj] = 0.f;
    float pp = 1.f;
    size_t base = ((size_t)b * Tsz + (size_t)c * CL) * Dsz + h * DH;
    float ewi = ew[base + i];
    float ki  = kk[base + i];
    const f32x4* vp = (const f32x4*)(vv + base + j0);
    f32x4 v0 = vp[0], v1 = vp[1], v2 = vp[2], v3 = vp[3];
    #pragma unroll 2
    for (int tt = 0; tt < CL; ++tt) {
        size_t nb = base + Dsz;
        float ewn = ew[nb + i];
        float kn  = kk[nb + i];
        const f32x4* np = (const f32x4*)(vv + nb + j0);
        f32x4 n0 = np[0], n1 = np[1], n2 = np[2], n3 = np[3];
        #pragma unroll
        for (int jj = 0; jj < 4; ++jj) {
            st[jj]      = fmaf(st[jj],      ewi, ki * v0[jj]);
            st[jj + 4]  = fmaf(st[jj + 4],  ewi, ki * v1[jj]);
            st[jj + 8]  = fmaf(st[jj + 8],  ewi, ki * v2[jj]);
            st[jj + 12] = fmaf(st[jj + 12], ewi, ki * v3[jj]);
        }
        pp *= ewi;
        ewi = ewn; ki = kn; v0 = n0; v1 = n1; v2 = n2; v3 = n3;
        base = nb;
    }
    size_t ob = (size_t)blk * 4096 + (size_t)i * 64 + j0;
    f32x4* op = (f32x4*)(Abuf + ob);
    #pragma unroll
    for (int g = 0; g < 4; ++g) {
        f32x4 s;
        #pragma unroll
        for (int jj = 0; jj < 4; ++jj) s[jj] = st[g * 4 + jj];
        op[g] = s;
    }
    if (q == 0) Pbuf[blk * 64 + i] = pp;
}

__global__ __launch_bounds__(256) void wkv_combine(const float* __restrict__ Abuf,
                                                   const float* __restrict__ Pbuf,
                                                   float* __restrict__ Sbuf) {
    int bh = blockIdx.x;
    int tid = threadIdx.x;
    int i = tid >> 2, q = tid & 3, j0 = q * 16;
    float s[16];
    #pragma unroll
    for (int jj = 0; jj < 16; ++jj) s[jj] = 0.f;
    // pipeline: preload chunk 0's A,P
    size_t ob0 = ((size_t)(bh * NC)) * 4096 + (size_t)i * 64 + j0;
    float pp = Pbuf[bh * NC * 64 + i];
    const f32x4* ap = (const f32x4*)(Abuf + ob0);
    f32x4 a0 = ap[0], a1 = ap[1], a2 = ap[2], a3 = ap[3];
    for (int c = 0; c < NC; ++c) {
        size_t ob = ((size_t)(bh * NC + c)) * 4096 + (size_t)i * 64 + j0;
        f32x4* sp = (f32x4*)(Sbuf + ob);
        #pragma unroll
        for (int g = 0; g < 4; ++g) {
            f32x4 t;
            #pragma unroll
            for (int jj = 0; jj < 4; ++jj) t[jj] = s[g * 4 + jj];
            sp[g] = t;
        }
        if (c < NC - 1) {
            float np;
            f32x4 b0, b1, b2, b3;
            if (c < NC - 2) {
                size_t nb = ob + 4096;
                np = Pbuf[(bh * NC + c + 1) * 64 + i];
                const f32x4* bp = (const f32x4*)(Abuf + nb);
                b0 = bp[0]; b1 = bp[1]; b2 = bp[2]; b3 = bp[3];
            }
            #pragma unroll
            for (int jj = 0; jj < 4; ++jj) {
                s[jj]      = s[jj]      * pp + a0[jj];
                s[jj + 4]  = s[jj + 4]  * pp + a1[jj];
                s[jj + 8]  = s[jj + 8]  * pp + a2[jj];
                s[jj + 12] = s[jj + 12] * pp + a3[jj];
            }
            if (c < NC - 2) { pp = np; a0 = b0; a1 = b1; a2 = b2; a3 = b3; }
        }
    }
}

__global__ __launch_bounds__(256) void wkv_pass2(const float* __restrict__ rr,
                                                 const float* __restrict__ kk,
                                                 const float* __restrict__ vv,
                                                 const float* __restrict__ ew,
                                                 const float* __restrict__ Sbuf,
                                                 float* __restrict__ o) {
    int blk = blockIdx.x;
    int bh = blk >> NCSH, c = blk & (NC - 1);
    int b = bh >> 4, h = bh & 15;
    int tid = threadIdx.x;
    int i = tid >> 2, q = tid & 3, j0 = q * 16;
    float st[16];
    {
        size_t ob = (size_t)blk * 4096 + (size_t)i * 64 + j0;
        const f32x4* sp = (const f32x4*)(Sbuf + ob);
        f32x4 s0 = sp[0], s1 = sp[1], s2 = sp[2], s3 = sp[3];
        #pragma unroll
        for (int jj = 0; jj < 4; ++jj) {
            st[jj] = s0[jj]; st[jj + 4] = s1[jj]; st[jj + 8] = s2[jj]; st[jj + 12] = s3[jj];
        }
    }
    size_t base = ((size_t)b * Tsz + (size_t)c * CL) * Dsz + h * DH;
    float ewi = ew[base + i];
    float ki  = kk[base + i];
    const f32x4* vp = (const f32x4*)(vv + base + j0);
    const f32x4* rp = (const f32x4*)(rr + base + j0);
    f32x4 v0 = vp[0], v1 = vp[1], v2 = vp[2], v3 = vp[3];
    f32x4 r0 = rp[0], r1 = rp[1], r2 = rp[2], r3 = rp[3];
    #pragma unroll 2
    for (int tt = 0; tt < CL; ++tt) {
        size_t nb = base + Dsz;
        float ewn = ew[nb + i];
        float kn  = kk[nb + i];
        const f32x4* np = (const f32x4*)(vv + nb + j0);
        const f32x4* mp = (const f32x4*)(rr + nb + j0);
        f32x4 n0 = np[0], n1 = np[1], n2 = np[2], n3 = np[3];
        f32x4 m0 = mp[0], m1 = mp[1], m2 = mp[2], m3 = mp[3];
        float po = 0.f;
        #pragma unroll
        for (int jj = 0; jj < 4; ++jj) {
            st[jj]      = fmaf(st[jj],      ewi, ki * v0[jj]);
            st[jj + 4]  = fmaf(st[jj + 4],  ewi, ki * v1[jj]);
            st[jj + 8]  = fmaf(st[jj + 8],  ewi, ki * v2[jj]);
            st[jj + 12] = fmaf(st[jj + 12], ewi, ki * v3[jj]);
            po = fmaf(st[jj],      r0[jj], po);
            po = fmaf(st[jj + 4],  r1[jj], po);
            po = fmaf(st[jj + 8],  r2[jj], po);
            po = fmaf(st[jj + 12], r3[jj], po);
        }
        po += __shfl_xor(po, 1, 64);
        po += __shfl_xor(po, 2, 64);
        if (q == 0) o[base + i] = po;
        ewi = ewn; ki = kn;
        v0 = n0; v1 = n1; v2 = n2; v3 = n3;
        r0 = m0; r1 = m1; r2 = m2; r3 = m3;
        base = nb;
    }
}

// ---------------------------------------------------------------------------
__global__ __launch_bounds__(256) void gn_gate(const float* __restrict__ o,
                                               const float* __restrict__ g,
                                               const float* __restrict__ gnw,
                                               const float* __restrict__ gnb,
                                               h16* __restrict__ out) {
    int wave = threadIdx.x >> 6, lane = threadIdx.x & 63;
    int grp = blockIdx.x * 4 + wave;     // tok*16 + h
    int h = grp & 15;
    float val = o[(size_t)grp * 64 + lane];
    float s = val, s2 = val * val;
    #pragma unroll
    for (int m = 1; m < 64; m <<= 1) {
        s  += __shfl_xor(s, m, 64);
        s2 += __shfl_xor(s2, m, 64);
    }
    float mean = s * (1.f / 64.f);
    float var  = s2 * (1.f / 64.f) - mean * mean;
    float y = (val - mean) * rsqrtf(var + 0.00064f);
    int d = h * 64 + lane;
    y = y * gnw[d] + gnb[d];
    y *= g[(size_t)grp * 64 + lane];
    out[(size_t)grp * 64 + lane] = (h16)y;
}

// ---------------------------------------------------------------------------
extern "C" void kernel_launch(void* const* d_in, const int* in_sizes, int n_in,
                              void* d_out, int out_size, void* d_ws, size_t ws_size,
                              hipStream_t stream) {
    const float* x      = (const float*)d_in[0];
    const float* ddw    = (const float*)d_in[1];
    const float* mix_r  = (const float*)d_in[2];
    const float* mix_k  = (const float*)d_in[3];
    const float* mix_v  = (const float*)d_in[4];
    const float* mix_g  = (const float*)d_in[5];
    const float* mix_w  = (const float*)d_in[6];
    const float* r_w    = (const float*)d_in[7];
    const float* k_w    = (const float*)d_in[8];
    const float* v_w    = (const float*)d_in[9];
    const float* g_w    = (const float*)d_in[10];
    const float* w_w    = (const float*)d_in[11];
    const float* out_w  = (const float*)d_in[12];
    const float* gnw    = (const float*)d_in[13];
    const float* gnb    = (const float*)d_in[14];

    char* wsb = (char*)d_ws;
    const size_t MB = 1 << 20;
    // persistent layout (contiguity of rb..ewb..obuf is REQUIRED by the
    // one-row overread in the scan pipeline):
    h16*   wb    = (h16*)  (wsb);             // 14 MB (7 x 2MB f16 weights)
    h16*   xs    = (h16*)  (wsb + 14 * MB);   //  8 MB
    float* dd    = (float*)(wsb + 22 * MB);   // 16 MB
    h16*   a_r   = (h16*)  (wsb + 38 * MB);   //  8 MB each
    h16*   a_k   = (h16*)  (wsb + 46 * MB);
    h16*   a_v   = (h16*)  (wsb + 54 * MB);
    h16*   a_g   = (h16*)  (wsb + 62 * MB);
    h16*   a_w   = (h16*)  (wsb + 70 * MB);
    float* rb    = (float*)(wsb + 78 * MB);   // 16 MB each
    float* kb    = (float*)(wsb + 94 * MB);
    float* vb    = (float*)(wsb + 110 * MB);
    float* gb    = (float*)(wsb + 126 * MB);
    float* ewb   = (float*)(wsb + 142 * MB);
    float* obuf  = (float*)(wsb + 158 * MB);  // 16 MB
    h16*   gated = (h16*)  (wsb + 174 * MB);  //  8 MB  (end: 182 MB)
    // overlays on the a_* region (dead once the 5 projections are done):
    float* Abuf  = (float*)(wsb + 38 * MB);   // 16.78 MB
    float* Sbuf  = (float*)(wsb + 55 * MB);   // 16.78 MB
    float* Pbuf  = (float*)(wsb + 72 * MB);   //  0.25 MB

    // 1. weights -> f16
    cvt_w7<<<7 * 512, 256, 0, stream>>>(ddw, r_w, k_w, v_w, g_w, w_w, out_w, wb);
    // 2. x_shift -> f16
    mk_xs<<<2048, 256, 0, stream>>>(x, xs);
    // 3. dd = sigmoid(tanh(xs @ ddw^T))
    dim3 gg(8, 32);
    gemm_bt<<<gg, 256, 0, stream>>>(xs, wb, dd, 1);
    // 4. 5-way lerp -> f16 activations
    lerp5<<<4096, 256, 0, stream>>>(x, dd, mix_r, mix_k, mix_v, mix_g, mix_w,
                                    a_r, a_k, a_v, a_g, a_w);
    // 5. batched projections (r,k,v,g-silu,w-exp)
    dim3 gg5(8, 32, 5);
    gemm5<<<gg5, 256, 0, stream>>>(a_r, a_k, a_v, a_g, a_w, wb, rb, kb, vb, gb, ewb);
    // 6-8. chunked WKV scan
    wkv_pass1<<<32 * NC, 256, 0, stream>>>(kb, vb, ewb, Abuf, Pbuf);
    wkv_combine<<<32, 256, 0, stream>>>(Abuf, Pbuf, Sbuf);
    wkv_pass2<<<32 * NC, 256, 0, stream>>>(rb, kb, vb, ewb, Sbuf, obuf);
    // 9. GroupNorm + gate
    gn_gate<<<(int)((size_t)Bsz * Tsz * Hn / 4), 256, 0, stream>>>(obuf, gb, gnw, gnb, gated);
    // 10. output projection
    gemm_bt<<<gg, 256, 0, stream>>>(gated, wb + 6 * 1048576, (float*)d_out, 0);
    (void)in_sizes; (void)n_in; (void)out_size; (void)ws_size;
}

// Round 4
// 287.673 us; speedup vs baseline: 1.6811x; 1.4899x over previous
//
#include <hip/hip_runtime.h>
#include <math.h>

typedef _Float16 h16;
typedef _Float16 h16x4 __attribute__((ext_vector_type(4)));
typedef _Float16 h16x8 __attribute__((ext_vector_type(8)));
typedef float    f32x4 __attribute__((ext_vector_type(4)));

#define Bsz 2
#define Tsz 2048
#define Dsz 1024
#define Hn  16
#define DH  64
#define NC  32         // scan chunks
#define NCSH 5
#define CL  (Tsz/NC)   // 64 steps per chunk
#define TS  16         // steps per LDS tile
#define NTL (CL/TS)    // 4 tiles per chunk
#define LP  68         // padded LDS row (floats): 4-way write conflict max

// ---------------------------------------------------------------------------
// Convert the 7 weight matrices (each 1024x1024 f32) to f16, packed at dst.
__global__ void cvt_w7(const float* __restrict__ s0, const float* __restrict__ s1,
                       const float* __restrict__ s2, const float* __restrict__ s3,
                       const float* __restrict__ s4, const float* __restrict__ s5,
                       const float* __restrict__ s6, h16* __restrict__ dst) {
    int seg = blockIdx.x >> 9;
    int li  = ((blockIdx.x & 511) << 8) + threadIdx.x;
    const float* sp;
    switch (seg) {
        case 0: sp = s0; break; case 1: sp = s1; break; case 2: sp = s2; break;
        case 3: sp = s3; break; case 4: sp = s4; break; case 5: sp = s5; break;
        default: sp = s6; break;
    }
    size_t e = (size_t)li * 8;
    f32x4 a = *(const f32x4*)(sp + e);
    f32x4 b = *(const f32x4*)(sp + e + 4);
    h16x8 o;
    #pragma unroll
    for (int j = 0; j < 4; ++j) { o[j] = (h16)a[j]; o[j + 4] = (h16)b[j]; }
    *(h16x8*)(dst + (size_t)seg * 1048576 + e) = o;
}

// ---------------------------------------------------------------------------
__global__ void mk_xs(const float* __restrict__ x, h16* __restrict__ xs) {
    int li = (blockIdx.x << 8) + threadIdx.x;
    size_t e = (size_t)li * 8;
    int tok = (int)(e >> 10);
    int t   = tok & (Tsz - 1);
    h16x8 o;
    if (t > 0) {
        f32x4 a = *(const f32x4*)(x + e - Dsz);
        f32x4 b = *(const f32x4*)(x + e - Dsz + 4);
        #pragma unroll
        for (int j = 0; j < 4; ++j) { o[j] = (h16)a[j]; o[j + 4] = (h16)b[j]; }
    } else {
        #pragma unroll
        for (int j = 0; j < 8; ++j) o[j] = (h16)0.f;
    }
    *(h16x8*)(xs + e) = o;
}

// ---------------------------------------------------------------------------
__global__ void lerp5(const float* __restrict__ x, const float* __restrict__ dd,
                      const float* __restrict__ mr, const float* __restrict__ mk,
                      const float* __restrict__ mv, const float* __restrict__ mg,
                      const float* __restrict__ mw,
                      h16* __restrict__ ar, h16* __restrict__ ak, h16* __restrict__ av,
                      h16* __restrict__ ag, h16* __restrict__ aw) {
    size_t e = ((size_t)blockIdx.x * 256 + threadIdx.x) * 4;
    int tok = (int)(e >> 10);
    int t   = tok & (Tsz - 1);
    int d   = (int)(e & (Dsz - 1));
    f32x4 xv = *(const f32x4*)(x + e);
    f32x4 xs;
    if (t > 0) xs = *(const f32x4*)(x + e - Dsz);
    else { xs[0] = xs[1] = xs[2] = xs[3] = 0.f; }
    f32x4 dv  = *(const f32x4*)(dd + e);
    f32x4 dxx = xv - xs;
    #define DOMIX(mp, outp) { \
        f32x4 mm = *(const f32x4*)(mp + d); \
        h16x4 ov; \
        _Pragma("unroll") \
        for (int jj = 0; jj < 4; ++jj) { \
            float m = mm[jj] + dv[jj] * (1.f - mm[jj]); \
            ov[jj] = (h16)(xs[jj] + dxx[jj] * m); \
        } \
        *(h16x4*)(outp + e) = ov; }
    DOMIX(mr, ar) DOMIX(mk, ak) DOMIX(mv, av) DOMIX(mg, ag) DOMIX(mw, aw)
    #undef DOMIX
}

// ---------------------------------------------------------------------------
// f16 MFMA GEMM body (unchanged this round).
#define KP 40
__device__ __forceinline__ void gemm_body(const h16* __restrict__ A,
                                          const h16* __restrict__ W,
                                          float* __restrict__ C, int epi) {
    __shared__ h16 As[128][KP];
    __shared__ h16 Bs[128][KP];
    const int tid  = threadIdx.x;
    const int lane = tid & 63;
    const int wave = tid >> 6;
    const int wm = (wave >> 1) * 64;
    const int wn = (wave & 1) * 64;
    const int bm = blockIdx.y * 128;
    const int bn = blockIdx.x * 128;
    const int K = 1024, N = 1024;

    f32x4 acc[4][4];
    #pragma unroll
    for (int a = 0; a < 4; ++a)
        #pragma unroll
        for (int b = 0; b < 4; ++b) acc[a][b] = (f32x4)(0.f);

    const int srow = tid >> 2;
    const int skc  = (tid & 3) * 8;

    for (int k0 = 0; k0 < K; k0 += 32) {
        f32x4 a0 = *(const f32x4*)(A + (size_t)(bm + srow)      * K + k0 + skc);
        f32x4 a1 = *(const f32x4*)(A + (size_t)(bm + srow + 64) * K + k0 + skc);
        f32x4 b0 = *(const f32x4*)(W + (size_t)(bn + srow)      * K + k0 + skc);
        f32x4 b1 = *(const f32x4*)(W + (size_t)(bn + srow + 64) * K + k0 + skc);
        __syncthreads();
        *(f32x4*)(&As[srow][skc])      = a0;
        *(f32x4*)(&As[srow + 64][skc]) = a1;
        *(f32x4*)(&Bs[srow][skc])      = b0;
        *(f32x4*)(&Bs[srow + 64][skc]) = b1;
        __syncthreads();
        h16x8 af[4], bfr[4];
        #pragma unroll
        for (int mi = 0; mi < 4; ++mi)
            af[mi] = *(const h16x8*)(&As[wm + mi * 16 + (lane & 15)][(lane >> 4) * 8]);
        #pragma unroll
        for (int ni = 0; ni < 4; ++ni)
            bfr[ni] = *(const h16x8*)(&Bs[wn + ni * 16 + (lane & 15)][(lane >> 4) * 8]);
        #pragma unroll
        for (int mi = 0; mi < 4; ++mi)
            #pragma unroll
            for (int ni = 0; ni < 4; ++ni)
                acc[mi][ni] = __builtin_amdgcn_mfma_f32_16x16x32_f16(
                    af[mi], bfr[ni], acc[mi][ni], 0, 0, 0);
    }

    const int colb = bn + wn + (lane & 15);
    const int rowb = bm + wm + (lane >> 4) * 4;
    #pragma unroll
    for (int mi = 0; mi < 4; ++mi)
        #pragma unroll
        for (int ni = 0; ni < 4; ++ni)
            #pragma unroll
            for (int j = 0; j < 4; ++j) {
                float y = acc[mi][ni][j];
                if (epi == 1)      { float th = tanhf(y); y = 1.f / (1.f + __expf(-th)); }
                else if (epi == 2) { y = y / (1.f + __expf(-y)); }
                else if (epi == 3) { y = 0.60653065971263342f / (1.f + __expf(-y)); }
                C[(size_t)(rowb + mi * 16 + j) * N + colb + ni * 16] = y;
            }
}

__global__ __launch_bounds__(256) void gemm_bt(const h16* __restrict__ A,
                                               const h16* __restrict__ W,
                                               float* __restrict__ C, int epi) {
    gemm_body(A, W, C, epi);
}

__global__ __launch_bounds__(256) void gemm5(const h16* __restrict__ A0, const h16* __restrict__ A1,
                                             const h16* __restrict__ A2, const h16* __restrict__ A3,
                                             const h16* __restrict__ A4, const h16* __restrict__ Wb,
                                             float* __restrict__ C0, float* __restrict__ C1,
                                             float* __restrict__ C2, float* __restrict__ C3,
                                             float* __restrict__ C4) {
    int z = blockIdx.z;
    const h16* A; float* C; int epi;
    switch (z) {
        case 0: A = A0; C = C0; epi = 0; break;
        case 1: A = A1; C = C1; epi = 0; break;
        case 2: A = A2; C = C2; epi = 0; break;
        case 3: A = A3; C = C3; epi = 2; break;
        default: A = A4; C = C4; epi = 3; break;
    }
    gemm_body(A, Wb + (size_t)(z + 1) * 1048576, C, epi);
}

// ---------------------------------------------------------------------------
// WKV scan with LDS-staged tiles (TS=16 steps), double-buffered, T14 split:
// issue global loads for tile t+1 -> regs; compute tile t from LDS;
// ds_write regs -> other buffer; barrier. Padded rows (LP=68) keep write
// conflicts at 4-way (1.58x) and read conflicts at 2-way (free).
// Thread t: row i=t>>2 (0..63), q=t&3 covers j in [q*16,q*16+16).
// Staging role: wave w loads array w (p1: waves 0-2 only).
__global__ __launch_bounds__(256) void wkv_pass1(const float* __restrict__ kk,
                                                 const float* __restrict__ vv,
                                                 const float* __restrict__ ew,
                                                 float* __restrict__ Abuf,
                                                 float* __restrict__ Pbuf) {
    __shared__ float lds[2][3][TS][LP];
    int blk = blockIdx.x;            // bh*NC + c
    int bh = blk >> NCSH, c = blk & (NC - 1);
    int b = bh >> 4, h = bh & 15;
    int tid = threadIdx.x;
    int i = tid >> 2, q = tid & 3, j0 = q * 16;
    int w = tid >> 6, idx = tid & 63;
    int ss = idx >> 2, qq = idx & 3;
    const float* sarr = (w == 0) ? ew : (w == 1) ? kk : vv;

    float st[16];
    #pragma unroll
    for (int jj = 0; jj < 16; ++jj) st[jj] = 0.f;
    float pp = 1.f;

    size_t cbase = ((size_t)b * Tsz + (size_t)c * CL) * Dsz + h * DH;

    if (w < 3) {   // prologue: stage tile 0
        const f32x4* g = (const f32x4*)(sarr + cbase + (size_t)ss * Dsz + qq * 16);
        f32x4 t0 = g[0], t1 = g[1], t2 = g[2], t3 = g[3];
        f32x4* d = (f32x4*)&lds[0][w][ss][qq * 16];
        d[0] = t0; d[1] = t1; d[2] = t2; d[3] = t3;
    }
    __syncthreads();

    for (int tl = 0; tl < NTL; ++tl) {
        int cur = tl & 1;
        f32x4 t0, t1, t2, t3;
        bool pf = (tl + 1 < NTL) && (w < 3);
        if (pf) {
            const f32x4* g = (const f32x4*)(sarr + cbase + (size_t)(tl + 1) * TS * Dsz
                                            + (size_t)ss * Dsz + qq * 16);
            t0 = g[0]; t1 = g[1]; t2 = g[2]; t3 = g[3];
        }
        #pragma unroll 4
        for (int s = 0; s < TS; ++s) {
            float ewi = lds[cur][0][s][i];
            float ki  = lds[cur][1][s][i];
            const float* vrow = &lds[cur][2][s][0];
            f32x4 v0 = *(const f32x4*)(vrow + j0);
            f32x4 v1 = *(const f32x4*)(vrow + j0 + 4);
            f32x4 v2 = *(const f32x4*)(vrow + j0 + 8);
            f32x4 v3 = *(const f32x4*)(vrow + j0 + 12);
            #pragma unroll
            for (int jj = 0; jj < 4; ++jj) {
                st[jj]      = fmaf(st[jj],      ewi, ki * v0[jj]);
                st[jj + 4]  = fmaf(st[jj + 4],  ewi, ki * v1[jj]);
                st[jj + 8]  = fmaf(st[jj + 8],  ewi, ki * v2[jj]);
                st[jj + 12] = fmaf(st[jj + 12], ewi, ki * v3[jj]);
            }
            pp *= ewi;
        }
        if (pf) {
            f32x4* d = (f32x4*)&lds[cur ^ 1][w][ss][qq * 16];
            d[0] = t0; d[1] = t1; d[2] = t2; d[3] = t3;
        }
        __syncthreads();
    }

    size_t ob = (size_t)blk * 4096 + (size_t)i * 64 + j0;
    f32x4* op = (f32x4*)(Abuf + ob);
    #pragma unroll
    for (int g = 0; g < 4; ++g) {
        f32x4 s;
        #pragma unroll
        for (int jj = 0; jj < 4; ++jj) s[jj] = st[g * 4 + jj];
        op[g] = s;
    }
    if (q == 0) Pbuf[blk * 64 + i] = pp;
}

__global__ __launch_bounds__(256) void wkv_combine(const float* __restrict__ Abuf,
                                                   const float* __restrict__ Pbuf,
                                                   float* __restrict__ Sbuf) {
    int bh = blockIdx.x;
    int tid = threadIdx.x;
    int i = tid >> 2, q = tid & 3, j0 = q * 16;
    float s[16];
    #pragma unroll
    for (int jj = 0; jj < 16; ++jj) s[jj] = 0.f;
    for (int c = 0; c < NC; ++c) {
        size_t ob = ((size_t)(bh * NC + c)) * 4096 + (size_t)i * 64 + j0;
        f32x4* sp = (f32x4*)(Sbuf + ob);
        #pragma unroll
        for (int g = 0; g < 4; ++g) {
            f32x4 t;
            #pragma unroll
            for (int jj = 0; jj < 4; ++jj) t[jj] = s[g * 4 + jj];
            sp[g] = t;
        }
        if (c < NC - 1) {
            float pp = Pbuf[(bh * NC + c) * 64 + i];
            const f32x4* ap = (const f32x4*)(Abuf + ob);
            f32x4 a0 = ap[0], a1 = ap[1], a2 = ap[2], a3 = ap[3];
            #pragma unroll
            for (int jj = 0; jj < 4; ++jj) {
                s[jj]      = s[jj]      * pp + a0[jj];
                s[jj + 4]  = s[jj + 4]  * pp + a1[jj];
                s[jj + 8]  = s[jj + 8]  * pp + a2[jj];
                s[jj + 12] = s[jj + 12] * pp + a3[jj];
            }
        }
    }
}

__global__ __launch_bounds__(256) void wkv_pass2(const float* __restrict__ rr,
                                                 const float* __restrict__ kk,
                                                 const float* __restrict__ vv,
                                                 const float* __restrict__ ew,
                                                 const float* __restrict__ Sbuf,
                                                 float* __restrict__ o) {
    __shared__ float lds[2][4][TS][LP];
    int blk = blockIdx.x;
    int bh = blk >> NCSH, c = blk & (NC - 1);
    int b = bh >> 4, h = bh & 15;
    int tid = threadIdx.x;
    int i = tid >> 2, q = tid & 3, j0 = q * 16;
    int w = tid >> 6, idx = tid & 63;
    int ss = idx >> 2, qq = idx & 3;
    const float* sarr = (w == 0) ? ew : (w == 1) ? kk : (w == 2) ? vv : rr;

    float st[16];
    {
        size_t ob = (size_t)blk * 4096 + (size_t)i * 64 + j0;
        const f32x4* sp = (const f32x4*)(Sbuf + ob);
        f32x4 s0 = sp[0], s1 = sp[1], s2 = sp[2], s3 = sp[3];
        #pragma unroll
        for (int jj = 0; jj < 4; ++jj) {
            st[jj] = s0[jj]; st[jj + 4] = s1[jj]; st[jj + 8] = s2[jj]; st[jj + 12] = s3[jj];
        }
    }

    size_t cbase = ((size_t)b * Tsz + (size_t)c * CL) * Dsz + h * DH;

    {   // prologue: stage tile 0
        const f32x4* g = (const f32x4*)(sarr + cbase + (size_t)ss * Dsz + qq * 16);
        f32x4 t0 = g[0], t1 = g[1], t2 = g[2], t3 = g[3];
        f32x4* d = (f32x4*)&lds[0][w][ss][qq * 16];
        d[0] = t0; d[1] = t1; d[2] = t2; d[3] = t3;
    }
    __syncthreads();

    for (int tl = 0; tl < NTL; ++tl) {
        int cur = tl & 1;
        f32x4 t0, t1, t2, t3;
        bool pf = (tl + 1 < NTL);
        if (pf) {
            const f32x4* g = (const f32x4*)(sarr + cbase + (size_t)(tl + 1) * TS * Dsz
                                            + (size_t)ss * Dsz + qq * 16);
            t0 = g[0]; t1 = g[1]; t2 = g[2]; t3 = g[3];
        }
        size_t gt = cbase + (size_t)tl * TS * Dsz;
        #pragma unroll 4
        for (int s = 0; s < TS; ++s) {
            float ewi = lds[cur][0][s][i];
            float ki  = lds[cur][1][s][i];
            const float* vrow = &lds[cur][2][s][0];
            const float* rrow = &lds[cur][3][s][0];
            f32x4 v0 = *(const f32x4*)(vrow + j0);
            f32x4 v1 = *(const f32x4*)(vrow + j0 + 4);
            f32x4 v2 = *(const f32x4*)(vrow + j0 + 8);
            f32x4 v3 = *(const f32x4*)(vrow + j0 + 12);
            f32x4 r0 = *(const f32x4*)(rrow + j0);
            f32x4 r1 = *(const f32x4*)(rrow + j0 + 4);
            f32x4 r2 = *(const f32x4*)(rrow + j0 + 8);
            f32x4 r3 = *(const f32x4*)(rrow + j0 + 12);
            float po = 0.f;
            #pragma unroll
            for (int jj = 0; jj < 4; ++jj) {
                st[jj]      = fmaf(st[jj],      ewi, ki * v0[jj]);
                st[jj + 4]  = fmaf(st[jj + 4],  ewi, ki * v1[jj]);
                st[jj + 8]  = fmaf(st[jj + 8],  ewi, ki * v2[jj]);
                st[jj + 12] = fmaf(st[jj + 12], ewi, ki * v3[jj]);
                po = fmaf(st[jj],      r0[jj], po);
                po = fmaf(st[jj + 4],  r1[jj], po);
                po = fmaf(st[jj + 8],  r2[jj], po);
                po = fmaf(st[jj + 12], r3[jj], po);
            }
            po += __shfl_xor(po, 1, 64);
            po += __shfl_xor(po, 2, 64);
            if (q == 0) o[gt + (size_t)s * Dsz + i] = po;
        }
        if (pf) {
            f32x4* d = (f32x4*)&lds[cur ^ 1][w][ss][qq * 16];
            d[0] = t0; d[1] = t1; d[2] = t2; d[3] = t3;
        }
        __syncthreads();
    }
}

// ---------------------------------------------------------------------------
__global__ __launch_bounds__(256) void gn_gate(const float* __restrict__ o,
                                               const float* __restrict__ g,
                                               const float* __restrict__ gnw,
                                               const float* __restrict__ gnb,
                                               h16* __restrict__ out) {
    int wave = threadIdx.x >> 6, lane = threadIdx.x & 63;
    int grp = blockIdx.x * 4 + wave;     // tok*16 + h
    int h = grp & 15;
    float val = o[(size_t)grp * 64 + lane];
    float s = val, s2 = val * val;
    #pragma unroll
    for (int m = 1; m < 64; m <<= 1) {
        s  += __shfl_xor(s, m, 64);
        s2 += __shfl_xor(s2, m, 64);
    }
    float mean = s * (1.f / 64.f);
    float var  = s2 * (1.f / 64.f) - mean * mean;
    float y = (val - mean) * rsqrtf(var + 0.00064f);
    int d = h * 64 + lane;
    y = y * gnw[d] + gnb[d];
    y *= g[(size_t)grp * 64 + lane];
    out[(size_t)grp * 64 + lane] = (h16)y;
}

// ---------------------------------------------------------------------------
extern "C" void kernel_launch(void* const* d_in, const int* in_sizes, int n_in,
                              void* d_out, int out_size, void* d_ws, size_t ws_size,
                              hipStream_t stream) {
    const float* x      = (const float*)d_in[0];
    const float* ddw    = (const float*)d_in[1];
    const float* mix_r  = (const float*)d_in[2];
    const float* mix_k  = (const float*)d_in[3];
    const float* mix_v  = (const float*)d_in[4];
    const float* mix_g  = (const float*)d_in[5];
    const float* mix_w  = (const float*)d_in[6];
    const float* r_w    = (const float*)d_in[7];
    const float* k_w    = (const float*)d_in[8];
    const float* v_w    = (const float*)d_in[9];
    const float* g_w    = (const float*)d_in[10];
    const float* w_w    = (const float*)d_in[11];
    const float* out_w  = (const float*)d_in[12];
    const float* gnw    = (const float*)d_in[13];
    const float* gnb    = (const float*)d_in[14];

    char* wsb = (char*)d_ws;
    const size_t MB = 1 << 20;
    h16*   wb    = (h16*)  (wsb);             // 14 MB (7 x 2MB f16 weights)
    h16*   xs    = (h16*)  (wsb + 14 * MB);   //  8 MB
    float* dd    = (float*)(wsb + 22 * MB);   // 16 MB
    h16*   a_r   = (h16*)  (wsb + 38 * MB);   //  8 MB each
    h16*   a_k   = (h16*)  (wsb + 46 * MB);
    h16*   a_v   = (h16*)  (wsb + 54 * MB);
    h16*   a_g   = (h16*)  (wsb + 62 * MB);
    h16*   a_w   = (h16*)  (wsb + 70 * MB);
    float* rb    = (float*)(wsb + 78 * MB);   // 16 MB each
    float* kb    = (float*)(wsb + 94 * MB);
    float* vb    = (float*)(wsb + 110 * MB);
    float* gb    = (float*)(wsb + 126 * MB);
    float* ewb   = (float*)(wsb + 142 * MB);
    float* obuf  = (float*)(wsb + 158 * MB);  // 16 MB
    h16*   gated = (h16*)  (wsb + 174 * MB);  //  8 MB  (end: 182 MB)
    // overlays on the a_* region (dead once the 5 projections are done):
    float* Abuf  = (float*)(wsb + 38 * MB);   // 16.78 MB
    float* Sbuf  = (float*)(wsb + 55 * MB);   // 16.78 MB
    float* Pbuf  = (float*)(wsb + 72 * MB);   //  0.25 MB

    // 1. weights -> f16
    cvt_w7<<<7 * 512, 256, 0, stream>>>(ddw, r_w, k_w, v_w, g_w, w_w, out_w, wb);
    // 2. x_shift -> f16
    mk_xs<<<2048, 256, 0, stream>>>(x, xs);
    // 3. dd = sigmoid(tanh(xs @ ddw^T))
    dim3 gg(8, 32);
    gemm_bt<<<gg, 256, 0, stream>>>(xs, wb, dd, 1);
    // 4. 5-way lerp -> f16 activations
    lerp5<<<4096, 256, 0, stream>>>(x, dd, mix_r, mix_k, mix_v, mix_g, mix_w,
                                    a_r, a_k, a_v, a_g, a_w);
    // 5. batched projections (r,k,v,g-silu,w-exp)
    dim3 gg5(8, 32, 5);
    gemm5<<<gg5, 256, 0, stream>>>(a_r, a_k, a_v, a_g, a_w, wb, rb, kb, vb, gb, ewb);
    // 6-8. chunked WKV scan
    wkv_pass1<<<32 * NC, 256, 0, stream>>>(kb, vb, ewb, Abuf, Pbuf);
    wkv_combine<<<32, 256, 0, stream>>>(Abuf, Pbuf, Sbuf);
    wkv_pass2<<<32 * NC, 256, 0, stream>>>(rb, kb, vb, ewb, Sbuf, obuf);
    // 9. GroupNorm + gate
    gn_gate<<<(int)((size_t)Bsz * Tsz * Hn / 4), 256, 0, stream>>>(obuf, gb, gnw, gnb, gated);
    // 10. output projection
    gemm_bt<<<gg, 256, 0, stream>>>(gated, wb + 6 * 1048576, (float*)d_out, 0);
    (void)in_sizes; (void)n_in; (void)out_size; (void)ws_size;
}